// Round 4
// baseline (214.025 us; speedup 1.0000x reference)
//
#include <hip/hip_runtime.h>

// Problem constants
#define B_SZ  4
#define C_IN  256
#define N_POS 4096     // H*W = 64*64
#define NH    2
#define HC    64       // hidden per head

typedef __attribute__((ext_vector_type(8))) __bf16 bf16x8;
typedef __attribute__((ext_vector_type(4))) float  f32x4;
typedef unsigned short u16;

__device__ __forceinline__ u16 f2bf(float f) {
  unsigned u = __float_as_uint(f);
  u = u + 0x7FFF + ((u >> 16) & 1);   // round-nearest-even
  return (u16)(u >> 16);
}

#if __has_builtin(__builtin_amdgcn_exp2f)
  #define EXP2(x) __builtin_amdgcn_exp2f(x)
#else
  #define EXP2(x) exp2f(x)
#endif

// packed f32x2 -> bf16x2 (RNE), low half = src0
__device__ __forceinline__ unsigned cvtpk_bf16(float lo, float hi) {
  unsigned r;
  asm("v_cvt_pk_bf16_f32 %0, %1, %2" : "=v"(r) : "v"(lo), "v"(hi));
  return r;
}

// ---------------------------------------------------------------------------
// Kernel 0a: x [B][C][N] fp32  ->  x_t [B][N][C] bf16  (transposed cast)
// ---------------------------------------------------------------------------
__global__ __launch_bounds__(256) void k_prep_x(const float* __restrict__ x,
                                                u16* __restrict__ xt) {
  __shared__ float tile[32][33];
  int b = blockIdx.z, c0 = blockIdx.y * 32, n0 = blockIdx.x * 32;
  int tx = threadIdx.x, ty = threadIdx.y;   // (32, 8)
  const float* src = x + ((size_t)b * C_IN + c0) * N_POS + n0;
#pragma unroll
  for (int i = 0; i < 4; i++) tile[ty + 8*i][tx] = src[(size_t)(ty + 8*i) * N_POS + tx];
  __syncthreads();
  u16* dst = xt + ((size_t)b * N_POS + n0) * C_IN + c0;
#pragma unroll
  for (int i = 0; i < 4; i++) dst[(size_t)(ty + 8*i) * C_IN + tx] = f2bf(tile[tx][ty + 8*i]);
}

// ---------------------------------------------------------------------------
// Kernel 0b: cast embed_w -> wbf [384][256] bf16 ; transpose out_w -> w2t [256][128] bf16
// ---------------------------------------------------------------------------
__global__ __launch_bounds__(256) void k_prep_w(const float* __restrict__ ew,
                                                const float* __restrict__ ow,
                                                u16* __restrict__ wbf,
                                                u16* __restrict__ w2t) {
  int i = blockIdx.x * 256 + threadIdx.x;
  if (i < 384 * 256) wbf[i] = f2bf(ew[i]);
  if (i < 128 * 256) {
    int d = i >> 8, c = i & 255;              // out_w[d][c]
    w2t[c * 128 + d] = f2bf(ow[i]);
  }
}

// ---------------------------------------------------------------------------
// Kernel 1: QKV projection.
//   q -> Qt [bh][N][64] (n-major, pre-scaled by C^-0.5 * log2(e))
//   k -> Kt [bh][N][64] (n-major)
//   v -> Vs [bh][nt(64)][kk(2)][lg(4)][c(64)][8]  (PV-fragment order)
// ---------------------------------------------------------------------------
__global__ __launch_bounds__(256) void k_qkv(const u16* __restrict__ xt,
                                             const u16* __restrict__ wbf,
                                             const float* __restrict__ eb,
                                             u16* __restrict__ Qt,
                                             u16* __restrict__ Kt,
                                             u16* __restrict__ Vs) {
  int b = blockIdx.z;          // 4
  int mt = blockIdx.y;         // 6
  int nt = blockIdx.x;         // 64
  int w = threadIdx.x >> 6, l = threadIdx.x & 63;
  int lr = l & 15, lg = l >> 4;
  int h = mt / 3, type = mt % 3;

  const u16* arow = xt + ((size_t)b * N_POS + nt*64 + w*16 + lr) * C_IN + lg*8;
  const u16* brow = wbf + ((size_t)(mt*64) + lr) * C_IN + lg*8;

  f32x4 acc[4] = {};
#pragma unroll
  for (int kk = 0; kk < 8; kk++) {
    bf16x8 a = *(const bf16x8*)(arow + kk*32);
#pragma unroll
    for (int mf = 0; mf < 4; mf++) {
      bf16x8 bf = *(const bf16x8*)(brow + (size_t)mf*16*C_IN + kk*32);
      acc[mf] = __builtin_amdgcn_mfma_f32_16x16x32_bf16(a, bf, acc[mf], 0, 0, 0);
    }
  }

  const float QSCALE = 0.0625f * 1.44269504088896f;  // C^-0.5 * log2(e)
  int bh = b * NH + h;
  int n0 = nt*64 + w*16 + lg*4;   // 4 consecutive n (regs)
#pragma unroll
  for (int mf = 0; mf < 4; mf++) {
    int cl = mf*16 + lr;                        // channel within head [0,64)
    float bias = eb[h*192 + type*64 + cl];
    if (type == 0) {
      u16* q = Qt + (size_t)bh * N_POS * HC;
#pragma unroll
      for (int r = 0; r < 4; r++) q[(size_t)(n0+r)*HC + cl] = f2bf((acc[mf][r] + bias) * QSCALE);
    } else if (type == 1) {
      u16* kd = Kt + (size_t)bh * N_POS * HC;
#pragma unroll
      for (int r = 0; r < 4; r++) kd[(size_t)(n0+r)*HC + cl] = f2bf(acc[mf][r] + bias);
    } else {
      // permuted V store: kk=w>>1, group=lg, e = 4*(w&1) + r
      u16* vd = Vs + (size_t)bh * (N_POS * HC);
      size_t idx = ((((size_t)nt*2 + (w>>1))*4 + lg)*64 + cl)*8 + 4*(w&1);
      ushort4 pk;
      pk.x = f2bf(acc[mf][0] + bias);
      pk.y = f2bf(acc[mf][1] + bias);
      pk.z = f2bf(acc[mf][2] + bias);
      pk.w = f2bf(acc[mf][3] + bias);
      *(ushort4*)(vd + idx) = pk;
    }
  }
}

// ---------------------------------------------------------------------------
// Kernel 2: flash attention, swapped-operand, NO max tracking (softmax is
// shift-invariant; |S*log2e| stays far below exp2's 127 range for this data
// distribution: sigma~1.4, overflow would need ~90 sigma). No cross-lane ops
// in the loop; rs reduced once at the end.
// ---------------------------------------------------------------------------
struct KB { bf16x8 k[4][2]; };
struct VB { bf16x8 v[2][4]; };

__device__ __forceinline__ void load_kb(KB& kb, const u16* kbase, int nt) {
#pragma unroll
  for (int nf = 0; nf < 4; nf++) {
    const u16* kp = kbase + (size_t)(nt*64 + nf*16) * HC;
    kb.k[nf][0] = *(const bf16x8*)kp;
    kb.k[nf][1] = *(const bf16x8*)(kp + 32);
  }
}

__device__ __forceinline__ void load_vb(VB& vb, const u16* vbase, int nt) {
#pragma unroll
  for (int kk = 0; kk < 2; kk++)
#pragma unroll
    for (int cf = 0; cf < 4; cf++)
      vb.v[kk][cf] = *(const bf16x8*)(vbase + (size_t)(nt*2 + kk)*2048 + cf*128);
}

__device__ __forceinline__ void attn_step(const KB& kb, const VB& vb,
                                          bf16x8 qf0, bf16x8 qf1,
                                          f32x4 (&o)[4], f32x4& psv) {
  union PF { bf16x8 v; unsigned u[4]; };
  // ---- S^T = K . Q^T  (lane: row m = lr, 16 n-values) ----
  f32x4 s[4];
#pragma unroll
  for (int nf = 0; nf < 4; nf++) {
    f32x4 z = {};
    z = __builtin_amdgcn_mfma_f32_16x16x32_bf16(kb.k[nf][0], qf0, z, 0, 0, 0);
    s[nf] = __builtin_amdgcn_mfma_f32_16x16x32_bf16(kb.k[nf][1], qf1, z, 0, 0, 0);
  }
  // ---- P = exp2(S), per-lane partial row-sum (4 parallel chains) ----
#pragma unroll
  for (int nf = 0; nf < 4; nf++)
#pragma unroll
    for (int r = 0; r < 4; r++) {
      float p = EXP2(s[nf][r]);
      s[nf][r] = p;
      psv[r] += p;
    }
  // ---- O^T += V^T . P ----
#pragma unroll
  for (int kk = 0; kk < 2; kk++) {
    PF pf;
    pf.u[0] = cvtpk_bf16(s[2*kk+0][0], s[2*kk+0][1]);
    pf.u[1] = cvtpk_bf16(s[2*kk+0][2], s[2*kk+0][3]);
    pf.u[2] = cvtpk_bf16(s[2*kk+1][0], s[2*kk+1][1]);
    pf.u[3] = cvtpk_bf16(s[2*kk+1][2], s[2*kk+1][3]);
#pragma unroll
    for (int cf = 0; cf < 4; cf++)
      o[cf] = __builtin_amdgcn_mfma_f32_16x16x32_bf16(vb.v[kk][cf], pf.v, o[cf], 0, 0, 0);
  }
}

__global__ __launch_bounds__(256) void k_attn(const u16* __restrict__ Qt,
                                              const u16* __restrict__ Kt,
                                              const u16* __restrict__ Vs,
                                              u16* __restrict__ Ot) {
  int id = blockIdx.x;            // 512
  int bh = id & 7;                // XCD-swizzle: one (b,h) per XCD
  int mt = id >> 3;               // 64 q-tiles
  int b = bh >> 1, h = bh & 1;
  int w = threadIdx.x >> 6, l = threadIdx.x & 63;
  int lr = l & 15, lg = l >> 4;
  int m0 = mt*64 + w*16;

  const u16* qbase = Qt + ((size_t)bh * N_POS + m0 + lr) * HC + lg*8;
  bf16x8 qf0 = *(const bf16x8*)(qbase);
  bf16x8 qf1 = *(const bf16x8*)(qbase + 32);

  const u16* kbase = Kt + (size_t)bh * N_POS * HC + (size_t)lr * HC + lg*8;
  const u16* vbase = Vs + (size_t)bh * (N_POS * HC) + (size_t)lg*512 + (size_t)lr*8;

  f32x4 o[4] = {};
  f32x4 psv = {};

  KB kA, kB; VB vA, vB;
  load_kb(kA, kbase, 0); load_vb(vA, vbase, 0);

  for (int nt = 0; nt < N_POS / 64; nt += 2) {
    load_kb(kB, kbase, nt + 1);
    load_vb(vB, vbase, nt + 1);
    attn_step(kA, vA, qf0, qf1, o, psv);
    load_kb(kA, kbase, nt + 2);   // at nt=62 reads tile 64: valid ws memory, unused
    load_vb(vA, vbase, nt + 2);
    attn_step(kB, vB, qf0, qf1, o, psv);
  }

  // ---- row-sum reduce (once) + normalize + write O_t [B][N][128] ----
  float ps = psv[0] + psv[1] + psv[2] + psv[3];
  ps += __shfl_xor(ps, 16);
  ps += __shfl_xor(ps, 32);
  float rinv = 1.0f / ps;
  u16* ob = Ot + ((size_t)b * N_POS + m0 + lr) * (NH*HC) + h*HC;
#pragma unroll
  for (int cf = 0; cf < 4; cf++) {
    ushort4 wv;
    wv.x = f2bf(o[cf][0] * rinv);
    wv.y = f2bf(o[cf][1] * rinv);
    wv.z = f2bf(o[cf][2] * rinv);
    wv.w = f2bf(o[cf][3] * rinv);
    *(ushort4*)(ob + cf*16 + 4*lg) = wv;
  }
}

// ---------------------------------------------------------------------------
// Kernel 3: out[b][c][n] = sum_d Ot[n][d] * w2t[c][d] + out_b[c] + x[b][c][n]
// ---------------------------------------------------------------------------
__global__ __launch_bounds__(256) void k_out(const u16* __restrict__ Ot,
                                             const u16* __restrict__ w2t,
                                             const float* __restrict__ obias,
                                             const float* __restrict__ x,
                                             float* __restrict__ out) {
  int b = blockIdx.z;   // 4
  int ct = blockIdx.y;  // 4
  int nt = blockIdx.x;  // 64
  int w = threadIdx.x >> 6, l = threadIdx.x & 63;
  int lr = l & 15, lg = l >> 4;

  const u16* arow = Ot + ((size_t)b * N_POS + nt*64 + w*16 + lr) * 128 + lg*8;
  const u16* brow = w2t + ((size_t)(ct*64) + lr) * 128 + lg*8;

  f32x4 acc[4] = {};
#pragma unroll
  for (int kk = 0; kk < 4; kk++) {
    bf16x8 a = *(const bf16x8*)(arow + kk*32);
#pragma unroll
    for (int cf = 0; cf < 4; cf++) {
      bf16x8 bf = *(const bf16x8*)(brow + (size_t)cf*16*128 + kk*32);
      acc[cf] = __builtin_amdgcn_mfma_f32_16x16x32_bf16(a, bf, acc[cf], 0, 0, 0);
    }
  }

  int n0 = nt*64 + w*16 + lg*4;
#pragma unroll
  for (int cf = 0; cf < 4; cf++) {
    int c = ct*64 + cf*16 + lr;
    float bias = obias[c];
    const float* xp = x + ((size_t)b * C_IN + c) * N_POS + n0;
    float* op = out + ((size_t)b * C_IN + c) * N_POS + n0;
    f32x4 xv = *(const f32x4*)xp;
    f32x4 rv;
#pragma unroll
    for (int i = 0; i < 4; i++) rv[i] = acc[cf][i] + bias + xv[i];
    *(f32x4*)op = rv;
  }
}

// ---------------------------------------------------------------------------
extern "C" void kernel_launch(void* const* d_in, const int* in_sizes, int n_in,
                              void* d_out, int out_size, void* d_ws, size_t ws_size,
                              hipStream_t stream) {
  const float* x  = (const float*)d_in[0];   // [4,256,64,64]
  const float* ew = (const float*)d_in[1];   // [2,192,256]
  const float* eb = (const float*)d_in[2];   // [2,192]
  const float* ow = (const float*)d_in[3];   // [128,256]
  const float* ob = (const float*)d_in[4];   // [256]
  float* out = (float*)d_out;

  char* ws = (char*)d_ws;
  u16* xt  = (u16*)(ws + 0);          //  8,388,608 B  x_t  [B][N][C]
  u16* wbf = (u16*)(ws + 8388608);    //    196,608 B  embed_w bf16 [384][256]
  u16* w2t = (u16*)(ws + 8585216);    //     65,536 B  out_w^T bf16 [256][128]
  u16* Qt  = (u16*)(ws + 8650752);    //  4,194,304 B  [8][4096][64]
  u16* Kt  = (u16*)(ws + 12845056);   //  4,194,304 B  [8][4096][64]
  u16* Vs  = (u16*)(ws + 17039360);   //  4,194,304 B  permuted V
  u16* Ot  = (u16*)(ws + 21233664);   //  4,194,304 B  [B][N][128]

  hipLaunchKernelGGL(k_prep_x, dim3(128, 8, 4), dim3(32, 8), 0, stream, x, xt);
  hipLaunchKernelGGL(k_prep_w, dim3(384), dim3(256), 0, stream, ew, ow, wbf, w2t);
  hipLaunchKernelGGL(k_qkv,  dim3(64, 6, 4), dim3(256), 0, stream, xt, wbf, eb, Qt, Kt, Vs);
  hipLaunchKernelGGL(k_attn, dim3(512),      dim3(256), 0, stream, Qt, Kt, Vs, Ot);
  hipLaunchKernelGGL(k_out,  dim3(64, 4, 4), dim3(256), 0, stream, Ot, w2t, ob, x, out);
}

// Round 6
// 202.950 us; speedup vs baseline: 1.0546x; 1.0546x over previous
//
#include <hip/hip_runtime.h>

// Problem constants
#define B_SZ  4
#define C_IN  256
#define N_POS 4096     // H*W = 64*64
#define NH    2
#define HC    64       // hidden per head

typedef __attribute__((ext_vector_type(8))) __bf16 bf16x8;
typedef __attribute__((ext_vector_type(4))) float  f32x4;
typedef unsigned short u16;

__device__ __forceinline__ u16 f2bf(float f) {
  unsigned u = __float_as_uint(f);
  u = u + 0x7FFF + ((u >> 16) & 1);   // round-nearest-even
  return (u16)(u >> 16);
}

#if __has_builtin(__builtin_amdgcn_exp2f)
  #define EXP2(x) __builtin_amdgcn_exp2f(x)
#else
  #define EXP2(x) exp2f(x)
#endif

// packed f32x2 -> bf16x2 (RNE), low half = src0
__device__ __forceinline__ unsigned cvtpk_bf16(float lo, float hi) {
  unsigned r;
  asm("v_cvt_pk_bf16_f32 %0, %1, %2" : "=v"(r) : "v"(lo), "v"(hi));
  return r;
}

// ---------------------------------------------------------------------------
// Kernel 0a: x [B][C][N] fp32  ->  x_t [B][N][C] bf16  (transposed cast)
// ---------------------------------------------------------------------------
__global__ __launch_bounds__(256) void k_prep_x(const float* __restrict__ x,
                                                u16* __restrict__ xt) {
  __shared__ float tile[32][33];
  int b = blockIdx.z, c0 = blockIdx.y * 32, n0 = blockIdx.x * 32;
  int tx = threadIdx.x, ty = threadIdx.y;   // (32, 8)
  const float* src = x + ((size_t)b * C_IN + c0) * N_POS + n0;
#pragma unroll
  for (int i = 0; i < 4; i++) tile[ty + 8*i][tx] = src[(size_t)(ty + 8*i) * N_POS + tx];
  __syncthreads();
  u16* dst = xt + ((size_t)b * N_POS + n0) * C_IN + c0;
#pragma unroll
  for (int i = 0; i < 4; i++) dst[(size_t)(ty + 8*i) * C_IN + tx] = f2bf(tile[tx][ty + 8*i]);
}

// ---------------------------------------------------------------------------
// Kernel 0b: cast embed_w -> wbf [384][256] bf16 ; transpose out_w -> w2t [256][128] bf16
// ---------------------------------------------------------------------------
__global__ __launch_bounds__(256) void k_prep_w(const float* __restrict__ ew,
                                                const float* __restrict__ ow,
                                                u16* __restrict__ wbf,
                                                u16* __restrict__ w2t) {
  int i = blockIdx.x * 256 + threadIdx.x;
  if (i < 384 * 256) wbf[i] = f2bf(ew[i]);
  if (i < 128 * 256) {
    int d = i >> 8, c = i & 255;              // out_w[d][c]
    w2t[c * 128 + d] = f2bf(ow[i]);
  }
}

// ---------------------------------------------------------------------------
// Kernel 1: QKV projection.
//   q -> Qt [bh][N][64] (n-major, pre-scaled by C^-0.5 * log2(e))
//   k -> Kt [bh][N][64] (n-major)
//   v -> Vs [bh][nt(64)][kk(2)][lg(4)][c(64)][8]  (PV-fragment order)
// ---------------------------------------------------------------------------
__global__ __launch_bounds__(256) void k_qkv(const u16* __restrict__ xt,
                                             const u16* __restrict__ wbf,
                                             const float* __restrict__ eb,
                                             u16* __restrict__ Qt,
                                             u16* __restrict__ Kt,
                                             u16* __restrict__ Vs) {
  int b = blockIdx.z;          // 4
  int mt = blockIdx.y;         // 6
  int nt = blockIdx.x;         // 64
  int w = threadIdx.x >> 6, l = threadIdx.x & 63;
  int lr = l & 15, lg = l >> 4;
  int h = mt / 3, type = mt % 3;

  const u16* arow = xt + ((size_t)b * N_POS + nt*64 + w*16 + lr) * C_IN + lg*8;
  const u16* brow = wbf + ((size_t)(mt*64) + lr) * C_IN + lg*8;

  f32x4 acc[4] = {};
#pragma unroll
  for (int kk = 0; kk < 8; kk++) {
    bf16x8 a = *(const bf16x8*)(arow + kk*32);
#pragma unroll
    for (int mf = 0; mf < 4; mf++) {
      bf16x8 bf = *(const bf16x8*)(brow + (size_t)mf*16*C_IN + kk*32);
      acc[mf] = __builtin_amdgcn_mfma_f32_16x16x32_bf16(a, bf, acc[mf], 0, 0, 0);
    }
  }

  const float QSCALE = 0.0625f * 1.44269504088896f;  // C^-0.5 * log2(e)
  int bh = b * NH + h;
  int n0 = nt*64 + w*16 + lg*4;   // 4 consecutive n (regs)
#pragma unroll
  for (int mf = 0; mf < 4; mf++) {
    int cl = mf*16 + lr;                        // channel within head [0,64)
    float bias = eb[h*192 + type*64 + cl];
    if (type == 0) {
      u16* q = Qt + (size_t)bh * N_POS * HC;
#pragma unroll
      for (int r = 0; r < 4; r++) q[(size_t)(n0+r)*HC + cl] = f2bf((acc[mf][r] + bias) * QSCALE);
    } else if (type == 1) {
      u16* kd = Kt + (size_t)bh * N_POS * HC;
#pragma unroll
      for (int r = 0; r < 4; r++) kd[(size_t)(n0+r)*HC + cl] = f2bf(acc[mf][r] + bias);
    } else {
      // permuted V store: kk=w>>1, group=lg, e = 4*(w&1) + r
      u16* vd = Vs + (size_t)bh * (N_POS * HC);
      size_t idx = ((((size_t)nt*2 + (w>>1))*4 + lg)*64 + cl)*8 + 4*(w&1);
      ushort4 pk;
      pk.x = f2bf(acc[mf][0] + bias);
      pk.y = f2bf(acc[mf][1] + bias);
      pk.z = f2bf(acc[mf][2] + bias);
      pk.w = f2bf(acc[mf][3] + bias);
      *(ushort4*)(vd + idx) = pk;
    }
  }
}

// ---------------------------------------------------------------------------
// Kernel 2: flash attention, swapped-operand, per-tile ONLINE MAX (round-3
// proven numerics), in-block split-KV: 16 waves = 4 q-subtiles x 4 KV-chunks
// (1024 positions each). Chunk partials (unnormalized O, row-sum ps, row max
// rm) merge exactly through LDS with exp2(rm_c - M) alignment.
// 512 blocks x 16 waves -> up to 8 waves/SIMD of TLP.
// ---------------------------------------------------------------------------
struct KB { bf16x8 k[4][2]; };
struct VB { bf16x8 v[2][4]; };

__device__ __forceinline__ void load_kb(KB& kb, const u16* kbase, int nt) {
#pragma unroll
  for (int nf = 0; nf < 4; nf++) {
    const u16* kp = kbase + (size_t)(nt*64 + nf*16) * HC;
    kb.k[nf][0] = *(const bf16x8*)kp;
    kb.k[nf][1] = *(const bf16x8*)(kp + 32);
  }
}

__device__ __forceinline__ void load_vb(VB& vb, const u16* vbase, int nt) {
#pragma unroll
  for (int kk = 0; kk < 2; kk++)
#pragma unroll
    for (int cf = 0; cf < 4; cf++)
      vb.v[kk][cf] = *(const bf16x8*)(vbase + (size_t)(nt*2 + kk)*2048 + cf*128);
}

__device__ __forceinline__ void attn_step(const KB& kb, const VB& vb,
                                          bf16x8 qf0, bf16x8 qf1,
                                          f32x4 (&o)[4], f32x4& psv, float& rm) {
  union PF { bf16x8 v; unsigned u[4]; };
  // ---- S^T = K . Q^T  (lane: row m = lane&15, 16 n-values) ----
  f32x4 s[4];
#pragma unroll
  for (int nf = 0; nf < 4; nf++) {
    f32x4 z = {};
    z = __builtin_amdgcn_mfma_f32_16x16x32_bf16(kb.k[nf][0], qf0, z, 0, 0, 0);
    s[nf] = __builtin_amdgcn_mfma_f32_16x16x32_bf16(kb.k[nf][1], qf1, z, 0, 0, 0);
  }
  // ---- online softmax with full per-tile max (log2 domain) ----
  float mx = s[0][0];
#pragma unroll
  for (int nf = 0; nf < 4; nf++)
#pragma unroll
    for (int r = 0; r < 4; r++) mx = fmaxf(mx, s[nf][r]);
  mx = fmaxf(mx, __shfl_xor(mx, 16));
  mx = fmaxf(mx, __shfl_xor(mx, 32));
  float nm = fmaxf(rm, mx);
  float corr = EXP2(rm - nm);
  rm = nm;
#pragma unroll
  for (int r = 0; r < 4; r++) psv[r] *= corr;
#pragma unroll
  for (int nf = 0; nf < 4; nf++)
#pragma unroll
    for (int r = 0; r < 4; r++) {
      float p = EXP2(s[nf][r] - nm);
      s[nf][r] = p;
      psv[r] += p;
    }
#pragma unroll
  for (int cf = 0; cf < 4; cf++)
#pragma unroll
    for (int r = 0; r < 4; r++) o[cf][r] *= corr;
  // ---- O^T += V^T . P ----
#pragma unroll
  for (int kk = 0; kk < 2; kk++) {
    PF pf;
    pf.u[0] = cvtpk_bf16(s[2*kk+0][0], s[2*kk+0][1]);
    pf.u[1] = cvtpk_bf16(s[2*kk+0][2], s[2*kk+0][3]);
    pf.u[2] = cvtpk_bf16(s[2*kk+1][0], s[2*kk+1][1]);
    pf.u[3] = cvtpk_bf16(s[2*kk+1][2], s[2*kk+1][3]);
#pragma unroll
    for (int cf = 0; cf < 4; cf++)
      o[cf] = __builtin_amdgcn_mfma_f32_16x16x32_bf16(vb.v[kk][cf], pf.v, o[cf], 0, 0, 0);
  }
}

__global__ __launch_bounds__(1024) void k_attn(const u16* __restrict__ Qt,
                                               const u16* __restrict__ Kt,
                                               const u16* __restrict__ Vs,
                                               u16* __restrict__ Ot) {
  int id = blockIdx.x;            // 512
  int bh = id & 7;                // XCD-swizzle: one (b,h) per XCD
  int mt = id >> 3;               // 64 q-tiles of 64 rows
  int b = bh >> 1, h = bh & 1;
  int tid = threadIdx.x;
  int wid = tid >> 6;             // 0..15
  int l = tid & 63, lr = l & 15, lg = l >> 4;
  int qi = wid & 3;               // q-subtile (16 rows)
  int ci = wid >> 2;              // KV chunk (16 tiles of 64 = 1024 positions)
  int m0 = mt*64 + qi*16;

  __shared__ float Lo[4][4][16][68];   // [ci][qi][row][c] (+4 pad)
  __shared__ float Lps[4][4][16];
  __shared__ float Lm[4][4][16];

  const u16* qbase = Qt + ((size_t)bh * N_POS + m0 + lr) * HC + lg*8;
  bf16x8 qf0 = *(const bf16x8*)(qbase);
  bf16x8 qf1 = *(const bf16x8*)(qbase + 32);

  const u16* kbase = Kt + (size_t)bh * N_POS * HC + (size_t)lr * HC + lg*8;
  const u16* vbase = Vs + (size_t)bh * (N_POS * HC) + (size_t)lg*512 + (size_t)lr*8;

  f32x4 o[4] = {};
  f32x4 psv = {};
  float rm = -1e30f;

  int T0 = ci * 16;
  for (int nt = T0; nt < T0 + 16; nt++) {
    KB kb; VB vb;
    load_kb(kb, kbase, nt);
    load_vb(vb, vbase, nt);
    attn_step(kb, vb, qf0, qf1, o, psv, rm);
  }

  // ---- chunk-partial row sum (row m = lr spans lanes lr, lr+16, lr+32, lr+48)
  float ps = psv[0] + psv[1] + psv[2] + psv[3];
  ps += __shfl_xor(ps, 16);
  ps += __shfl_xor(ps, 32);

  // ---- write partials ----
#pragma unroll
  for (int cf = 0; cf < 4; cf++)
    *(f32x4*)&Lo[ci][qi][lr][cf*16 + 4*lg] = o[cf];
  if (lg == 0) { Lps[ci][qi][lr] = ps; Lm[ci][qi][lr] = rm; }
  __syncthreads();

  // ---- exact flash merge of 4 chunks + normalize + write Ot [B][N][128] ----
  int row = tid >> 4;             // 0..63 within this q-tile
  int c0 = (tid & 15) * 4;        // 0..60
  int q2 = row >> 4, r2 = row & 15;
  float m0_ = Lm[0][q2][r2], m1_ = Lm[1][q2][r2];
  float m2_ = Lm[2][q2][r2], m3_ = Lm[3][q2][r2];
  float M = fmaxf(fmaxf(m0_, m1_), fmaxf(m2_, m3_));
  float w0 = EXP2(m0_ - M), w1 = EXP2(m1_ - M);
  float w2 = EXP2(m2_ - M), w3 = EXP2(m3_ - M);
  f32x4 a0 = *(const f32x4*)&Lo[0][q2][r2][c0];
  f32x4 a1 = *(const f32x4*)&Lo[1][q2][r2][c0];
  f32x4 a2 = *(const f32x4*)&Lo[2][q2][r2][c0];
  f32x4 a3 = *(const f32x4*)&Lo[3][q2][r2][c0];
  f32x4 acc;
#pragma unroll
  for (int i = 0; i < 4; i++) acc[i] = a0[i]*w0 + a1[i]*w1 + a2[i]*w2 + a3[i]*w3;
  float pst = Lps[0][q2][r2]*w0 + Lps[1][q2][r2]*w1
            + Lps[2][q2][r2]*w2 + Lps[3][q2][r2]*w3;
  float rinv = 1.0f / pst;
  u16* ob = Ot + ((size_t)b * N_POS + mt*64 + row) * (NH*HC) + h*HC + c0;
  ushort4 wv;
  wv.x = f2bf(acc[0] * rinv);
  wv.y = f2bf(acc[1] * rinv);
  wv.z = f2bf(acc[2] * rinv);
  wv.w = f2bf(acc[3] * rinv);
  *(ushort4*)ob = wv;
}

// ---------------------------------------------------------------------------
// Kernel 3: out[b][c][n] = sum_d Ot[n][d] * w2t[c][d] + out_b[c] + x[b][c][n]
// ---------------------------------------------------------------------------
__global__ __launch_bounds__(256) void k_out(const u16* __restrict__ Ot,
                                             const u16* __restrict__ w2t,
                                             const float* __restrict__ obias,
                                             const float* __restrict__ x,
                                             float* __restrict__ out) {
  int b = blockIdx.z;   // 4
  int ct = blockIdx.y;  // 4
  int nt = blockIdx.x;  // 64
  int w = threadIdx.x >> 6, l = threadIdx.x & 63;
  int lr = l & 15, lg = l >> 4;

  const u16* arow = Ot + ((size_t)b * N_POS + nt*64 + w*16 + lr) * 128 + lg*8;
  const u16* brow = w2t + ((size_t)(ct*64) + lr) * 128 + lg*8;

  f32x4 acc[4] = {};
#pragma unroll
  for (int kk = 0; kk < 4; kk++) {
    bf16x8 a = *(const bf16x8*)(arow + kk*32);
#pragma unroll
    for (int cf = 0; cf < 4; cf++) {
      bf16x8 bf = *(const bf16x8*)(brow + (size_t)cf*16*128 + kk*32);
      acc[cf] = __builtin_amdgcn_mfma_f32_16x16x32_bf16(a, bf, acc[cf], 0, 0, 0);
    }
  }

  int n0 = nt*64 + w*16 + lg*4;
#pragma unroll
  for (int cf = 0; cf < 4; cf++) {
    int c = ct*64 + cf*16 + lr;
    float bias = obias[c];
    const float* xp = x + ((size_t)b * C_IN + c) * N_POS + n0;
    float* op = out + ((size_t)b * C_IN + c) * N_POS + n0;
    f32x4 xv = *(const f32x4*)xp;
    f32x4 rv;
#pragma unroll
    for (int i = 0; i < 4; i++) rv[i] = acc[cf][i] + bias + xv[i];
    *(f32x4*)op = rv;
  }
}

// ---------------------------------------------------------------------------
extern "C" void kernel_launch(void* const* d_in, const int* in_sizes, int n_in,
                              void* d_out, int out_size, void* d_ws, size_t ws_size,
                              hipStream_t stream) {
  const float* x  = (const float*)d_in[0];   // [4,256,64,64]
  const float* ew = (const float*)d_in[1];   // [2,192,256]
  const float* eb = (const float*)d_in[2];   // [2,192]
  const float* ow = (const float*)d_in[3];   // [128,256]
  const float* ob = (const float*)d_in[4];   // [256]
  float* out = (float*)d_out;

  char* ws = (char*)d_ws;
  u16* xt  = (u16*)(ws + 0);          //  8,388,608 B  x_t  [B][N][C]
  u16* wbf = (u16*)(ws + 8388608);    //    196,608 B  embed_w bf16 [384][256]
  u16* w2t = (u16*)(ws + 8585216);    //     65,536 B  out_w^T bf16 [256][128]
  u16* Qt  = (u16*)(ws + 8650752);    //  4,194,304 B  [8][4096][64]
  u16* Kt  = (u16*)(ws + 12845056);   //  4,194,304 B  [8][4096][64]
  u16* Vs  = (u16*)(ws + 17039360);   //  4,194,304 B  permuted V
  u16* Ot  = (u16*)(ws + 21233664);   //  4,194,304 B  [B][N][128]

  hipLaunchKernelGGL(k_prep_x, dim3(128, 8, 4), dim3(32, 8), 0, stream, x, xt);
  hipLaunchKernelGGL(k_prep_w, dim3(384), dim3(256), 0, stream, ew, ow, wbf, w2t);
  hipLaunchKernelGGL(k_qkv,  dim3(64, 6, 4), dim3(256), 0, stream, xt, wbf, eb, Qt, Kt, Vs);
  hipLaunchKernelGGL(k_attn, dim3(512),      dim3(1024), 0, stream, Qt, Kt, Vs, Ot);
  hipLaunchKernelGGL(k_out,  dim3(64, 4, 4), dim3(256), 0, stream, Ot, w2t, ob, x, out);
}

// Round 7
// 110.424 us; speedup vs baseline: 1.9382x; 1.8379x over previous
//
#include <hip/hip_runtime.h>

// Problem constants
#define B_SZ  4
#define C_IN  256
#define N_POS 4096     // H*W = 64*64
#define NH    2
#define HC    64       // hidden per head

typedef __attribute__((ext_vector_type(8))) __bf16 bf16x8;
typedef __attribute__((ext_vector_type(4))) float  f32x4;
typedef unsigned short u16;

__device__ __forceinline__ u16 f2bf(float f) {
  unsigned u = __float_as_uint(f);
  u = u + 0x7FFF + ((u >> 16) & 1);   // round-nearest-even
  return (u16)(u >> 16);
}

#if __has_builtin(__builtin_amdgcn_exp2f)
  #define EXP2(x) __builtin_amdgcn_exp2f(x)
#else
  #define EXP2(x) exp2f(x)
#endif

// packed f32x2 -> bf16x2 (RNE), low half = src0
__device__ __forceinline__ unsigned cvtpk_bf16(float lo, float hi) {
  unsigned r;
  asm("v_cvt_pk_bf16_f32 %0, %1, %2" : "=v"(r) : "v"(lo), "v"(hi));
  return r;
}

// ---------------------------------------------------------------------------
// Kernel 0a: x [B][C][N] fp32  ->  x_t [B][N][C] bf16  (transposed cast)
// ---------------------------------------------------------------------------
__global__ __launch_bounds__(256) void k_prep_x(const float* __restrict__ x,
                                                u16* __restrict__ xt) {
  __shared__ float tile[32][33];
  int b = blockIdx.z, c0 = blockIdx.y * 32, n0 = blockIdx.x * 32;
  int tx = threadIdx.x, ty = threadIdx.y;   // (32, 8)
  const float* src = x + ((size_t)b * C_IN + c0) * N_POS + n0;
#pragma unroll
  for (int i = 0; i < 4; i++) tile[ty + 8*i][tx] = src[(size_t)(ty + 8*i) * N_POS + tx];
  __syncthreads();
  u16* dst = xt + ((size_t)b * N_POS + n0) * C_IN + c0;
#pragma unroll
  for (int i = 0; i < 4; i++) dst[(size_t)(ty + 8*i) * C_IN + tx] = f2bf(tile[tx][ty + 8*i]);
}

// ---------------------------------------------------------------------------
// Kernel 0b: cast embed_w -> wbf [384][256] bf16 ; transpose out_w -> w2t [256][128] bf16
// ---------------------------------------------------------------------------
__global__ __launch_bounds__(256) void k_prep_w(const float* __restrict__ ew,
                                                const float* __restrict__ ow,
                                                u16* __restrict__ wbf,
                                                u16* __restrict__ w2t) {
  int i = blockIdx.x * 256 + threadIdx.x;
  if (i < 384 * 256) wbf[i] = f2bf(ew[i]);
  if (i < 128 * 256) {
    int d = i >> 8, c = i & 255;              // out_w[d][c]
    w2t[c * 128 + d] = f2bf(ow[i]);
  }
}

// ---------------------------------------------------------------------------
// Kernel 1: QKV projection.
//   q -> Qt [bh][N][64] (n-major, pre-scaled by C^-0.5 * log2(e))
//   k -> Kt [bh][N][64] (n-major)
//   v -> Vs [bh][nt(64)][kk(2)][lg(4)][c(64)][8]  (PV-fragment order)
// ---------------------------------------------------------------------------
__global__ __launch_bounds__(256) void k_qkv(const u16* __restrict__ xt,
                                             const u16* __restrict__ wbf,
                                             const float* __restrict__ eb,
                                             u16* __restrict__ Qt,
                                             u16* __restrict__ Kt,
                                             u16* __restrict__ Vs) {
  int b = blockIdx.z;          // 4
  int mt = blockIdx.y;         // 6
  int nt = blockIdx.x;         // 64
  int w = threadIdx.x >> 6, l = threadIdx.x & 63;
  int lr = l & 15, lg = l >> 4;
  int h = mt / 3, type = mt % 3;

  const u16* arow = xt + ((size_t)b * N_POS + nt*64 + w*16 + lr) * C_IN + lg*8;
  const u16* brow = wbf + ((size_t)(mt*64) + lr) * C_IN + lg*8;

  f32x4 acc[4] = {};
#pragma unroll
  for (int kk = 0; kk < 8; kk++) {
    bf16x8 a = *(const bf16x8*)(arow + kk*32);
#pragma unroll
    for (int mf = 0; mf < 4; mf++) {
      bf16x8 bf = *(const bf16x8*)(brow + (size_t)mf*16*C_IN + kk*32);
      acc[mf] = __builtin_amdgcn_mfma_f32_16x16x32_bf16(a, bf, acc[mf], 0, 0, 0);
    }
  }

  const float QSCALE = 0.0625f * 1.44269504088896f;  // C^-0.5 * log2(e)
  int bh = b * NH + h;
  int n0 = nt*64 + w*16 + lg*4;   // 4 consecutive n (regs)
#pragma unroll
  for (int mf = 0; mf < 4; mf++) {
    int cl = mf*16 + lr;                        // channel within head [0,64)
    float bias = eb[h*192 + type*64 + cl];
    if (type == 0) {
      u16* q = Qt + (size_t)bh * N_POS * HC;
#pragma unroll
      for (int r = 0; r < 4; r++) q[(size_t)(n0+r)*HC + cl] = f2bf((acc[mf][r] + bias) * QSCALE);
    } else if (type == 1) {
      u16* kd = Kt + (size_t)bh * N_POS * HC;
#pragma unroll
      for (int r = 0; r < 4; r++) kd[(size_t)(n0+r)*HC + cl] = f2bf(acc[mf][r] + bias);
    } else {
      // permuted V store: kk=w>>1, group=lg, e = 4*(w&1) + r
      u16* vd = Vs + (size_t)bh * (N_POS * HC);
      size_t idx = ((((size_t)nt*2 + (w>>1))*4 + lg)*64 + cl)*8 + 4*(w&1);
      ushort4 pk;
      pk.x = f2bf(acc[mf][0] + bias);
      pk.y = f2bf(acc[mf][1] + bias);
      pk.z = f2bf(acc[mf][2] + bias);
      pk.w = f2bf(acc[mf][3] + bias);
      *(ushort4*)(vd + idx) = pk;
    }
  }
}

// ---------------------------------------------------------------------------
// Kernel 2: flash attention. 16 waves = 4 qi x 4 ci. Each ci-group stages its
// K/V tile into LDS (reg-staged, double-buffered, XOR-swizzled K) so the 4
// qi-waves share one L2 read. Swapped-operand MFMA + per-tile online max
// (round-6 proven numerics) + LDS merge of 4 chunk partials.
// ---------------------------------------------------------------------------
__global__ __launch_bounds__(1024, 4) void k_attn(const u16* __restrict__ Qt,
                                                  const u16* __restrict__ Kt,
                                                  const u16* __restrict__ Vs,
                                                  u16* __restrict__ Ot) {
  int id = blockIdx.x;            // 512
  int bh = id & 7;                // XCD-swizzle: one (b,h) per XCD
  int mt = id >> 3;               // 64 q-tiles of 64 rows
  int b = bh >> 1, h = bh & 1;
  int tid = threadIdx.x;
  int wid = tid >> 6;             // 0..15
  int l = tid & 63, lr = l & 15, lg = l >> 4;
  int qi = wid & 3;               // q-subtile (16 rows)
  int ci = wid >> 2;              // KV chunk (16 tiles of 64 = 1024 positions)
  int m0 = mt*64 + qi*16;

  // 128KB staging: [buf2][ci4][ K 8KB | V 8KB ]; merge overlays after loop
  __shared__ __align__(16) char smem[131072];
  __shared__ float Lps[4][4][16];
  __shared__ float Lm[4][4][16];

  const u16* qbase = Qt + ((size_t)bh * N_POS + m0 + lr) * HC + lg*8;
  bf16x8 qf0 = *(const bf16x8*)(qbase);
  bf16x8 qf1 = *(const bf16x8*)(qbase + 32);

  const char* Kt_bh = (const char*)(Kt + (size_t)bh * N_POS * HC);
  const char* Vs_bh = (const char*)(Vs + (size_t)bh * N_POS * HC);

  int gtid = tid & 255;           // index within ci staging group (256 threads)

  f32x4 o[4] = {};
  f32x4 psv = {};
  float rm = -1e30f;
  int xr = (lr & 7) << 4;         // K read swizzle (row&7 == lr&7 since 16|row base)

  union PF { bf16x8 v; unsigned u[4]; };

  // ---- prologue: stage tile ci*16 into buf 0 ----
  {
    const uint4* ksrc = (const uint4*)(Kt_bh + (size_t)(ci*16) * 8192);
    const uint4* vsrc = (const uint4*)(Vs_bh + (size_t)(ci*16) * 8192);
    char* sb = smem + ci*16384;
#pragma unroll
    for (int j = 0; j < 2; j++) {
      int goff = (j*256 + gtid) * 16;
      uint4 kv = ksrc[j*256 + gtid];
      uint4 vv = vsrc[j*256 + gtid];
      *(uint4*)(sb + (goff ^ (((goff >> 7) & 7) << 4))) = kv;   // swizzled K
      *(uint4*)(sb + 8192 + goff) = vv;                          // linear V
    }
  }
  __syncthreads();

  int buf = 0;
  for (int t = 0; t < 16; t++) {
    // ---- issue next tile's global loads early (latency hides under compute)
    uint4 kreg[2], vreg[2];
    bool pf = (t + 1 < 16);
    if (pf) {
      const uint4* ksrc = (const uint4*)(Kt_bh + (size_t)(ci*16 + t + 1) * 8192);
      const uint4* vsrc = (const uint4*)(Vs_bh + (size_t)(ci*16 + t + 1) * 8192);
#pragma unroll
      for (int j = 0; j < 2; j++) { kreg[j] = ksrc[j*256 + gtid]; vreg[j] = vsrc[j*256 + gtid]; }
    }

    // ---- compute from buf ----
    const char* Kb = smem + buf*65536 + ci*16384;
    const char* Vb = Kb + 8192;

    f32x4 s[4];
#pragma unroll
    for (int nf = 0; nf < 4; nf++) {
      const char* kr = Kb + (nf*16 + lr) * 128;
      bf16x8 k0 = *(const bf16x8*)(kr + ((lg*16)      ^ xr));
      bf16x8 k1 = *(const bf16x8*)(kr + ((lg*16 + 64) ^ xr));
      f32x4 z = {};
      z = __builtin_amdgcn_mfma_f32_16x16x32_bf16(k0, qf0, z, 0, 0, 0);
      s[nf] = __builtin_amdgcn_mfma_f32_16x16x32_bf16(k1, qf1, z, 0, 0, 0);
    }
    // online softmax with per-tile max (log2 domain)
    float mx = s[0][0];
#pragma unroll
    for (int nf = 0; nf < 4; nf++)
#pragma unroll
      for (int r = 0; r < 4; r++) mx = fmaxf(mx, s[nf][r]);
    mx = fmaxf(mx, __shfl_xor(mx, 16));
    mx = fmaxf(mx, __shfl_xor(mx, 32));
    float nm = fmaxf(rm, mx);
    float corr = EXP2(rm - nm);
    rm = nm;
#pragma unroll
    for (int r = 0; r < 4; r++) psv[r] *= corr;
#pragma unroll
    for (int nf = 0; nf < 4; nf++)
#pragma unroll
      for (int r = 0; r < 4; r++) {
        float p = EXP2(s[nf][r] - nm);
        s[nf][r] = p;
        psv[r] += p;
      }
#pragma unroll
    for (int cf = 0; cf < 4; cf++)
#pragma unroll
      for (int r = 0; r < 4; r++) o[cf][r] *= corr;
    // O^T += V^T . P
#pragma unroll
    for (int kk = 0; kk < 2; kk++) {
      PF pfr;
      pfr.u[0] = cvtpk_bf16(s[2*kk+0][0], s[2*kk+0][1]);
      pfr.u[1] = cvtpk_bf16(s[2*kk+0][2], s[2*kk+0][3]);
      pfr.u[2] = cvtpk_bf16(s[2*kk+1][0], s[2*kk+1][1]);
      pfr.u[3] = cvtpk_bf16(s[2*kk+1][2], s[2*kk+1][3]);
#pragma unroll
      for (int cf = 0; cf < 4; cf++) {
        bf16x8 vf = *(const bf16x8*)(Vb + (kk*4 + lg)*1024 + (cf*16 + lr)*16);
        o[cf] = __builtin_amdgcn_mfma_f32_16x16x32_bf16(vf, pfr.v, o[cf], 0, 0, 0);
      }
    }

    // ---- write staged regs to the other buffer ----
    if (pf) {
      char* sb = smem + (buf^1)*65536 + ci*16384;
#pragma unroll
      for (int j = 0; j < 2; j++) {
        int goff = (j*256 + gtid) * 16;
        *(uint4*)(sb + (goff ^ (((goff >> 7) & 7) << 4))) = kreg[j];
        *(uint4*)(sb + 8192 + goff) = vreg[j];
      }
    }
    __syncthreads();
    buf ^= 1;
  }

  // ---- chunk-partial row sum ----
  float ps = psv[0] + psv[1] + psv[2] + psv[3];
  ps += __shfl_xor(ps, 16);
  ps += __shfl_xor(ps, 32);

  // ---- write partials (Lo overlays the staging LDS — safe after last barrier)
  float (*Lo)[4][16][68] = (float (*)[4][16][68])smem;
#pragma unroll
  for (int cf = 0; cf < 4; cf++)
    *(f32x4*)&Lo[ci][qi][lr][cf*16 + 4*lg] = o[cf];
  if (lg == 0) { Lps[ci][qi][lr] = ps; Lm[ci][qi][lr] = rm; }
  __syncthreads();

  // ---- exact flash merge of 4 chunks + normalize + write Ot [B][N][128] ----
  int row = tid >> 4;             // 0..63 within this q-tile
  int c0 = (tid & 15) * 4;        // 0..60
  int q2 = row >> 4, r2 = row & 15;
  float m0_ = Lm[0][q2][r2], m1_ = Lm[1][q2][r2];
  float m2_ = Lm[2][q2][r2], m3_ = Lm[3][q2][r2];
  float M = fmaxf(fmaxf(m0_, m1_), fmaxf(m2_, m3_));
  float w0 = EXP2(m0_ - M), w1 = EXP2(m1_ - M);
  float w2 = EXP2(m2_ - M), w3 = EXP2(m3_ - M);
  f32x4 a0 = *(const f32x4*)&Lo[0][q2][r2][c0];
  f32x4 a1 = *(const f32x4*)&Lo[1][q2][r2][c0];
  f32x4 a2 = *(const f32x4*)&Lo[2][q2][r2][c0];
  f32x4 a3 = *(const f32x4*)&Lo[3][q2][r2][c0];
  f32x4 acc;
#pragma unroll
  for (int i = 0; i < 4; i++) acc[i] = a0[i]*w0 + a1[i]*w1 + a2[i]*w2 + a3[i]*w3;
  float pst = Lps[0][q2][r2]*w0 + Lps[1][q2][r2]*w1
            + Lps[2][q2][r2]*w2 + Lps[3][q2][r2]*w3;
  float rinv = 1.0f / pst;
  u16* ob = Ot + ((size_t)b * N_POS + mt*64 + row) * (NH*HC) + h*HC + c0;
  ushort4 wv;
  wv.x = f2bf(acc[0] * rinv);
  wv.y = f2bf(acc[1] * rinv);
  wv.z = f2bf(acc[2] * rinv);
  wv.w = f2bf(acc[3] * rinv);
  *(ushort4*)ob = wv;
}

// ---------------------------------------------------------------------------
// Kernel 3: out[b][c][n] = sum_d Ot[n][d] * w2t[c][d] + out_b[c] + x[b][c][n]
// ---------------------------------------------------------------------------
__global__ __launch_bounds__(256) void k_out(const u16* __restrict__ Ot,
                                             const u16* __restrict__ w2t,
                                             const float* __restrict__ obias,
                                             const float* __restrict__ x,
                                             float* __restrict__ out) {
  int b = blockIdx.z;   // 4
  int ct = blockIdx.y;  // 4
  int nt = blockIdx.x;  // 64
  int w = threadIdx.x >> 6, l = threadIdx.x & 63;
  int lr = l & 15, lg = l >> 4;

  const u16* arow = Ot + ((size_t)b * N_POS + nt*64 + w*16 + lr) * 128 + lg*8;
  const u16* brow = w2t + ((size_t)(ct*64) + lr) * 128 + lg*8;

  f32x4 acc[4] = {};
#pragma unroll
  for (int kk = 0; kk < 4; kk++) {
    bf16x8 a = *(const bf16x8*)(arow + kk*32);
#pragma unroll
    for (int cf = 0; cf < 4; cf++) {
      bf16x8 bf = *(const bf16x8*)(brow + (size_t)cf*16*128 + kk*32);
      acc[cf] = __builtin_amdgcn_mfma_f32_16x16x32_bf16(a, bf, acc[cf], 0, 0, 0);
    }
  }

  int n0 = nt*64 + w*16 + lg*4;
#pragma unroll
  for (int cf = 0; cf < 4; cf++) {
    int c = ct*64 + cf*16 + lr;
    float bias = obias[c];
    const float* xp = x + ((size_t)b * C_IN + c) * N_POS + n0;
    float* op = out + ((size_t)b * C_IN + c) * N_POS + n0;
    f32x4 xv = *(const f32x4*)xp;
    f32x4 rv;
#pragma unroll
    for (int i = 0; i < 4; i++) rv[i] = acc[cf][i] + bias + xv[i];
    *(f32x4*)op = rv;
  }
}

// ---------------------------------------------------------------------------
extern "C" void kernel_launch(void* const* d_in, const int* in_sizes, int n_in,
                              void* d_out, int out_size, void* d_ws, size_t ws_size,
                              hipStream_t stream) {
  const float* x  = (const float*)d_in[0];   // [4,256,64,64]
  const float* ew = (const float*)d_in[1];   // [2,192,256]
  const float* eb = (const float*)d_in[2];   // [2,192]
  const float* ow = (const float*)d_in[3];   // [128,256]
  const float* ob = (const float*)d_in[4];   // [256]
  float* out = (float*)d_out;

  char* ws = (char*)d_ws;
  u16* xt  = (u16*)(ws + 0);          //  8,388,608 B  x_t  [B][N][C]
  u16* wbf = (u16*)(ws + 8388608);    //    196,608 B  embed_w bf16 [384][256]
  u16* w2t = (u16*)(ws + 8585216);    //     65,536 B  out_w^T bf16 [256][128]
  u16* Qt  = (u16*)(ws + 8650752);    //  4,194,304 B  [8][4096][64]
  u16* Kt  = (u16*)(ws + 12845056);   //  4,194,304 B  [8][4096][64]
  u16* Vs  = (u16*)(ws + 17039360);   //  4,194,304 B  permuted V
  u16* Ot  = (u16*)(ws + 21233664);   //  4,194,304 B  [B][N][128]

  hipLaunchKernelGGL(k_prep_x, dim3(128, 8, 4), dim3(32, 8), 0, stream, x, xt);
  hipLaunchKernelGGL(k_prep_w, dim3(384), dim3(256), 0, stream, ew, ow, wbf, w2t);
  hipLaunchKernelGGL(k_qkv,  dim3(64, 6, 4), dim3(256), 0, stream, xt, wbf, eb, Qt, Kt, Vs);
  hipLaunchKernelGGL(k_attn, dim3(512),      dim3(1024), 0, stream, Qt, Kt, Vs, Ot);
  hipLaunchKernelGGL(k_out,  dim3(64, 4, 4), dim3(256), 0, stream, Ot, w2t, ob, x, out);
}

// Round 8
// 105.910 us; speedup vs baseline: 2.0208x; 1.0426x over previous
//
#include <hip/hip_runtime.h>

// Problem constants
#define B_SZ  4
#define C_IN  256
#define N_POS 4096     // H*W = 64*64
#define NH    2
#define HC    64       // hidden per head

typedef __attribute__((ext_vector_type(8))) __bf16 bf16x8;
typedef __attribute__((ext_vector_type(4))) float  f32x4;
typedef unsigned short u16;

__device__ __forceinline__ u16 f2bf(float f) {
  unsigned u = __float_as_uint(f);
  u = u + 0x7FFF + ((u >> 16) & 1);   // round-nearest-even
  return (u16)(u >> 16);
}

#if __has_builtin(__builtin_amdgcn_exp2f)
  #define EXP2(x) __builtin_amdgcn_exp2f(x)
#else
  #define EXP2(x) exp2f(x)
#endif

// packed f32x2 -> bf16x2 (RNE), low half = src0
__device__ __forceinline__ unsigned cvtpk_bf16(float lo, float hi) {
  unsigned r;
  asm("v_cvt_pk_bf16_f32 %0, %1, %2" : "=v"(r) : "v"(lo), "v"(hi));
  return r;
}

// async global->LDS 16B per lane (dest = wave-uniform base + lane*16)
__device__ __forceinline__ void gload_lds16(const void* g, void* l) {
  __builtin_amdgcn_global_load_lds(
      (const __attribute__((address_space(1))) unsigned*)g,
      (__attribute__((address_space(3))) unsigned*)l, 16, 0, 0);
}

// ---------------------------------------------------------------------------
// Kernel 0a: x [B][C][N] fp32  ->  x_t [B][N][C] bf16  (transposed cast)
// ---------------------------------------------------------------------------
__global__ __launch_bounds__(256) void k_prep_x(const float* __restrict__ x,
                                                u16* __restrict__ xt) {
  __shared__ float tile[32][33];
  int b = blockIdx.z, c0 = blockIdx.y * 32, n0 = blockIdx.x * 32;
  int tx = threadIdx.x, ty = threadIdx.y;   // (32, 8)
  const float* src = x + ((size_t)b * C_IN + c0) * N_POS + n0;
#pragma unroll
  for (int i = 0; i < 4; i++) tile[ty + 8*i][tx] = src[(size_t)(ty + 8*i) * N_POS + tx];
  __syncthreads();
  u16* dst = xt + ((size_t)b * N_POS + n0) * C_IN + c0;
#pragma unroll
  for (int i = 0; i < 4; i++) dst[(size_t)(ty + 8*i) * C_IN + tx] = f2bf(tile[tx][ty + 8*i]);
}

// ---------------------------------------------------------------------------
// Kernel 0b: cast embed_w -> wbf [384][256] bf16 ; transpose out_w -> w2t [256][128] bf16
// ---------------------------------------------------------------------------
__global__ __launch_bounds__(256) void k_prep_w(const float* __restrict__ ew,
                                                const float* __restrict__ ow,
                                                u16* __restrict__ wbf,
                                                u16* __restrict__ w2t) {
  int i = blockIdx.x * 256 + threadIdx.x;
  if (i < 384 * 256) wbf[i] = f2bf(ew[i]);
  if (i < 128 * 256) {
    int d = i >> 8, c = i & 255;              // out_w[d][c]
    w2t[c * 128 + d] = f2bf(ow[i]);
  }
}

// ---------------------------------------------------------------------------
// Kernel 1: QKV projection.
//   q -> Qt [bh][N][64] (n-major, pre-scaled by C^-0.5 * log2(e))
//   k -> Kt [bh][N][64] (n-major)
//   v -> Vs [bh][nt(64)][kk(2)][lg(4)][c(64)][8]  (PV-fragment order)
// ---------------------------------------------------------------------------
__global__ __launch_bounds__(256) void k_qkv(const u16* __restrict__ xt,
                                             const u16* __restrict__ wbf,
                                             const float* __restrict__ eb,
                                             u16* __restrict__ Qt,
                                             u16* __restrict__ Kt,
                                             u16* __restrict__ Vs) {
  int b = blockIdx.z;          // 4
  int mt = blockIdx.y;         // 6
  int nt = blockIdx.x;         // 64
  int w = threadIdx.x >> 6, l = threadIdx.x & 63;
  int lr = l & 15, lg = l >> 4;
  int h = mt / 3, type = mt % 3;

  const u16* arow = xt + ((size_t)b * N_POS + nt*64 + w*16 + lr) * C_IN + lg*8;
  const u16* brow = wbf + ((size_t)(mt*64) + lr) * C_IN + lg*8;

  f32x4 acc[4] = {};
#pragma unroll
  for (int kk = 0; kk < 8; kk++) {
    bf16x8 a = *(const bf16x8*)(arow + kk*32);
#pragma unroll
    for (int mf = 0; mf < 4; mf++) {
      bf16x8 bf = *(const bf16x8*)(brow + (size_t)mf*16*C_IN + kk*32);
      acc[mf] = __builtin_amdgcn_mfma_f32_16x16x32_bf16(a, bf, acc[mf], 0, 0, 0);
    }
  }

  const float QSCALE = 0.0625f * 1.44269504088896f;  // C^-0.5 * log2(e)
  int bh = b * NH + h;
  int n0 = nt*64 + w*16 + lg*4;   // 4 consecutive n (regs)
#pragma unroll
  for (int mf = 0; mf < 4; mf++) {
    int cl = mf*16 + lr;                        // channel within head [0,64)
    float bias = eb[h*192 + type*64 + cl];
    if (type == 0) {
      u16* q = Qt + (size_t)bh * N_POS * HC;
#pragma unroll
      for (int r = 0; r < 4; r++) q[(size_t)(n0+r)*HC + cl] = f2bf((acc[mf][r] + bias) * QSCALE);
    } else if (type == 1) {
      u16* kd = Kt + (size_t)bh * N_POS * HC;
#pragma unroll
      for (int r = 0; r < 4; r++) kd[(size_t)(n0+r)*HC + cl] = f2bf(acc[mf][r] + bias);
    } else {
      // permuted V store: kk=w>>1, group=lg, e = 4*(w&1) + r
      u16* vd = Vs + (size_t)bh * (N_POS * HC);
      size_t idx = ((((size_t)nt*2 + (w>>1))*4 + lg)*64 + cl)*8 + 4*(w&1);
      ushort4 pk;
      pk.x = f2bf(acc[mf][0] + bias);
      pk.y = f2bf(acc[mf][1] + bias);
      pk.z = f2bf(acc[mf][2] + bias);
      pk.w = f2bf(acc[mf][3] + bias);
      *(ushort4*)(vd + idx) = pk;
    }
  }
}

// ---------------------------------------------------------------------------
// Kernel 2: flash attention. 16 waves = 4 qi x 4 ci; each wave owns 32 q-rows
// (2 fragments) so each K/V LDS read feeds 2 MFMAs (32 FLOP/B from LDS).
// Staging via global_load_lds (K with inverse-swizzled source, read swizzled).
// Per-16-row online-max softmax + exact LDS merge of 4 chunk partials.
// Grid 256 = 1 block/CU.
// ---------------------------------------------------------------------------
__device__ __forceinline__ void softmax_tile(f32x4 (&s)[4], f32x4& psv, float& rm,
                                             f32x4 (&o)[4]) {
  float mx = s[0][0];
#pragma unroll
  for (int nf = 0; nf < 4; nf++)
#pragma unroll
    for (int r = 0; r < 4; r++) mx = fmaxf(mx, s[nf][r]);
  mx = fmaxf(mx, __shfl_xor(mx, 16));
  mx = fmaxf(mx, __shfl_xor(mx, 32));
  float nm = fmaxf(rm, mx);
  float corr = EXP2(rm - nm);
  rm = nm;
#pragma unroll
  for (int r = 0; r < 4; r++) psv[r] *= corr;
#pragma unroll
  for (int nf = 0; nf < 4; nf++)
#pragma unroll
    for (int r = 0; r < 4; r++) {
      float p = EXP2(s[nf][r] - nm);
      s[nf][r] = p;
      psv[r] += p;
    }
#pragma unroll
  for (int cf = 0; cf < 4; cf++)
#pragma unroll
    for (int r = 0; r < 4; r++) o[cf][r] *= corr;
}

__global__ __launch_bounds__(1024, 4) void k_attn(const u16* __restrict__ Qt,
                                                  const u16* __restrict__ Kt,
                                                  const u16* __restrict__ Vs,
                                                  u16* __restrict__ Ot) {
  int id = blockIdx.x;            // 256
  int bh = id & 7;                // XCD-swizzle: one (b,h) per XCD
  int mt = id >> 3;               // 32 q-tiles of 128 rows
  int b = bh >> 1, h = bh & 1;
  int tid = threadIdx.x;
  int wid = tid >> 6;             // 0..15
  int l = tid & 63, lr = l & 15, lg = l >> 4;
  int qi = wid & 3;               // 32-row q-subtile
  int ci = wid >> 2;              // KV chunk (16 tiles of 64 = 1024 positions)
  int m0 = mt*128 + qi*32;

  // 128KB staging: [buf2][ci4][ K 8KB | V 8KB ]; merge overlays after loop
  __shared__ __align__(16) char smem[131072];
  __shared__ float Lps[4][8][16];
  __shared__ float Lm[4][8][16];

  bf16x8 qf[2][2];
#pragma unroll
  for (int sub = 0; sub < 2; sub++) {
    const u16* qb = Qt + ((size_t)bh * N_POS + m0 + sub*16 + lr) * HC + lg*8;
    qf[sub][0] = *(const bf16x8*)qb;
    qf[sub][1] = *(const bf16x8*)(qb + 32);
  }

  const char* Kt_bh = (const char*)(Kt + (size_t)bh * N_POS * HC);
  const char* Vs_bh = (const char*)(Vs + (size_t)bh * N_POS * HC);
  int gtid = tid & 255;           // index within ci staging group (256 threads)

  f32x4 o0[4] = {}, o1[4] = {};
  f32x4 ps0 = {}, ps1 = {};
  float rm0 = -1e30f, rm1 = -1e30f;
  int xr = (lr & 7) << 4;         // K read swizzle

  union PF { bf16x8 v; unsigned u[4]; };

  // stage tile -> LDS: K with inverse-swizzled SOURCE (linear dest), V linear
  auto stage = [&](int tile, char* sb) {
    const char* ksrc = Kt_bh + (size_t)tile * 8192;
    const char* vsrc = Vs_bh + (size_t)tile * 8192;
#pragma unroll
    for (int j = 0; j < 2; j++) {
      int off = (j*256 + gtid) * 16;
      int koff = off ^ (((off >> 7) & 7) << 4);
      gload_lds16(ksrc + koff, sb + off);
      gload_lds16(vsrc + off, sb + 8192 + off);
    }
  };

  stage(ci*16, smem + ci*16384);
  __syncthreads();

  int buf = 0;
  for (int t = 0; t < 16; t++) {
    if (t < 15) stage(ci*16 + t + 1, smem + (buf^1)*65536 + ci*16384);

    const char* Kb = smem + buf*65536 + ci*16384;
    const char* Vb = Kb + 8192;

    // ---- S^T = K . Q^T for both q-subtiles (K read once) ----
    f32x4 s0[4], s1[4];
#pragma unroll
    for (int nf = 0; nf < 4; nf++) {
      const char* kr = Kb + (nf*16 + lr) * 128;
      bf16x8 k0 = *(const bf16x8*)(kr + ((lg*16)      ^ xr));
      bf16x8 k1 = *(const bf16x8*)(kr + ((lg*16 + 64) ^ xr));
      f32x4 z0 = {}, z1 = {};
      z0 = __builtin_amdgcn_mfma_f32_16x16x32_bf16(k0, qf[0][0], z0, 0, 0, 0);
      s0[nf] = __builtin_amdgcn_mfma_f32_16x16x32_bf16(k1, qf[0][1], z0, 0, 0, 0);
      z1 = __builtin_amdgcn_mfma_f32_16x16x32_bf16(k0, qf[1][0], z1, 0, 0, 0);
      s1[nf] = __builtin_amdgcn_mfma_f32_16x16x32_bf16(k1, qf[1][1], z1, 0, 0, 0);
    }

    softmax_tile(s0, ps0, rm0, o0);
    softmax_tile(s1, ps1, rm1, o1);

    // ---- O^T += V^T . P (V read once, feeds both subtiles) ----
#pragma unroll
    for (int kk = 0; kk < 2; kk++) {
      PF pa, pb;
      pa.u[0] = cvtpk_bf16(s0[2*kk+0][0], s0[2*kk+0][1]);
      pa.u[1] = cvtpk_bf16(s0[2*kk+0][2], s0[2*kk+0][3]);
      pa.u[2] = cvtpk_bf16(s0[2*kk+1][0], s0[2*kk+1][1]);
      pa.u[3] = cvtpk_bf16(s0[2*kk+1][2], s0[2*kk+1][3]);
      pb.u[0] = cvtpk_bf16(s1[2*kk+0][0], s1[2*kk+0][1]);
      pb.u[1] = cvtpk_bf16(s1[2*kk+0][2], s1[2*kk+0][3]);
      pb.u[2] = cvtpk_bf16(s1[2*kk+1][0], s1[2*kk+1][1]);
      pb.u[3] = cvtpk_bf16(s1[2*kk+1][2], s1[2*kk+1][3]);
#pragma unroll
      for (int cf = 0; cf < 4; cf++) {
        bf16x8 vf = *(const bf16x8*)(Vb + (kk*4 + lg)*1024 + (cf*16 + lr)*16);
        o0[cf] = __builtin_amdgcn_mfma_f32_16x16x32_bf16(vf, pa.v, o0[cf], 0, 0, 0);
        o1[cf] = __builtin_amdgcn_mfma_f32_16x16x32_bf16(vf, pb.v, o1[cf], 0, 0, 0);
      }
    }

    __syncthreads();   // drains vmcnt -> next buffer ready
    buf ^= 1;
  }

  // ---- chunk-partial row sums ----
  float psa = ps0[0] + ps0[1] + ps0[2] + ps0[3];
  psa += __shfl_xor(psa, 16);
  psa += __shfl_xor(psa, 32);
  float psb = ps1[0] + ps1[1] + ps1[2] + ps1[3];
  psb += __shfl_xor(psb, 16);
  psb += __shfl_xor(psb, 32);

  // ---- write partials (Lo overlays staging LDS — safe after last barrier) ----
  float (*Lo)[8][16][64] = (float (*)[8][16][64])smem;
#pragma unroll
  for (int cf = 0; cf < 4; cf++) {
    *(f32x4*)&Lo[ci][qi*2+0][lr][cf*16 + 4*lg] = o0[cf];
    *(f32x4*)&Lo[ci][qi*2+1][lr][cf*16 + 4*lg] = o1[cf];
  }
  if (lg == 0) {
    Lps[ci][qi*2+0][lr] = psa; Lm[ci][qi*2+0][lr] = rm0;
    Lps[ci][qi*2+1][lr] = psb; Lm[ci][qi*2+1][lr] = rm1;
  }
  __syncthreads();

  // ---- exact flash merge of 4 chunks + normalize + write Ot [B][N][128] ----
  int row = tid >> 3;             // 0..127 within this q-tile
  int c0 = (tid & 7) * 8;         // 0..56
  int g = row >> 4, r2 = row & 15;
  float m0_ = Lm[0][g][r2], m1_ = Lm[1][g][r2];
  float m2_ = Lm[2][g][r2], m3_ = Lm[3][g][r2];
  float M = fmaxf(fmaxf(m0_, m1_), fmaxf(m2_, m3_));
  float w0 = EXP2(m0_ - M), w1 = EXP2(m1_ - M);
  float w2 = EXP2(m2_ - M), w3 = EXP2(m3_ - M);
  f32x4 accA, accB;
  {
    f32x4 a0 = *(const f32x4*)&Lo[0][g][r2][c0];
    f32x4 a1 = *(const f32x4*)&Lo[1][g][r2][c0];
    f32x4 a2 = *(const f32x4*)&Lo[2][g][r2][c0];
    f32x4 a3 = *(const f32x4*)&Lo[3][g][r2][c0];
#pragma unroll
    for (int i = 0; i < 4; i++) accA[i] = a0[i]*w0 + a1[i]*w1 + a2[i]*w2 + a3[i]*w3;
    f32x4 b0 = *(const f32x4*)&Lo[0][g][r2][c0+4];
    f32x4 b1 = *(const f32x4*)&Lo[1][g][r2][c0+4];
    f32x4 b2 = *(const f32x4*)&Lo[2][g][r2][c0+4];
    f32x4 b3 = *(const f32x4*)&Lo[3][g][r2][c0+4];
#pragma unroll
    for (int i = 0; i < 4; i++) accB[i] = b0[i]*w0 + b1[i]*w1 + b2[i]*w2 + b3[i]*w3;
  }
  float pst = Lps[0][g][r2]*w0 + Lps[1][g][r2]*w1
            + Lps[2][g][r2]*w2 + Lps[3][g][r2]*w3;
  float rinv = 1.0f / pst;
  u16* ob = Ot + ((size_t)b * N_POS + mt*128 + row) * (NH*HC) + h*HC + c0;
  uint4 st;
  st.x = cvtpk_bf16(accA[0]*rinv, accA[1]*rinv);
  st.y = cvtpk_bf16(accA[2]*rinv, accA[3]*rinv);
  st.z = cvtpk_bf16(accB[0]*rinv, accB[1]*rinv);
  st.w = cvtpk_bf16(accB[2]*rinv, accB[3]*rinv);
  *(uint4*)ob = st;
}

// ---------------------------------------------------------------------------
// Kernel 3: out[b][c][n] = sum_d Ot[n][d] * w2t[c][d] + out_b[c] + x[b][c][n]
// ---------------------------------------------------------------------------
__global__ __launch_bounds__(256) void k_out(const u16* __restrict__ Ot,
                                             const u16* __restrict__ w2t,
                                             const float* __restrict__ obias,
                                             const float* __restrict__ x,
                                             float* __restrict__ out) {
  int b = blockIdx.z;   // 4
  int ct = blockIdx.y;  // 4
  int nt = blockIdx.x;  // 64
  int w = threadIdx.x >> 6, l = threadIdx.x & 63;
  int lr = l & 15, lg = l >> 4;

  const u16* arow = Ot + ((size_t)b * N_POS + nt*64 + w*16 + lr) * 128 + lg*8;
  const u16* brow = w2t + ((size_t)(ct*64) + lr) * 128 + lg*8;

  f32x4 acc[4] = {};
#pragma unroll
  for (int kk = 0; kk < 4; kk++) {
    bf16x8 a = *(const bf16x8*)(arow + kk*32);
#pragma unroll
    for (int cf = 0; cf < 4; cf++) {
      bf16x8 bf = *(const bf16x8*)(brow + (size_t)cf*16*128 + kk*32);
      acc[cf] = __builtin_amdgcn_mfma_f32_16x16x32_bf16(a, bf, acc[cf], 0, 0, 0);
    }
  }

  int n0 = nt*64 + w*16 + lg*4;
#pragma unroll
  for (int cf = 0; cf < 4; cf++) {
    int c = ct*64 + cf*16 + lr;
    float bias = obias[c];
    const float* xp = x + ((size_t)b * C_IN + c) * N_POS + n0;
    float* op = out + ((size_t)b * C_IN + c) * N_POS + n0;
    f32x4 xv = *(const f32x4*)xp;
    f32x4 rv;
#pragma unroll
    for (int i = 0; i < 4; i++) rv[i] = acc[cf][i] + bias + xv[i];
    *(f32x4*)op = rv;
  }
}

// ---------------------------------------------------------------------------
extern "C" void kernel_launch(void* const* d_in, const int* in_sizes, int n_in,
                              void* d_out, int out_size, void* d_ws, size_t ws_size,
                              hipStream_t stream) {
  const float* x  = (const float*)d_in[0];   // [4,256,64,64]
  const float* ew = (const float*)d_in[1];   // [2,192,256]
  const float* eb = (const float*)d_in[2];   // [2,192]
  const float* ow = (const float*)d_in[3];   // [128,256]
  const float* ob = (const float*)d_in[4];   // [256]
  float* out = (float*)d_out;

  char* ws = (char*)d_ws;
  u16* xt  = (u16*)(ws + 0);          //  8,388,608 B  x_t  [B][N][C]
  u16* wbf = (u16*)(ws + 8388608);    //    196,608 B  embed_w bf16 [384][256]
  u16* w2t = (u16*)(ws + 8585216);    //     65,536 B  out_w^T bf16 [256][128]
  u16* Qt  = (u16*)(ws + 8650752);    //  4,194,304 B  [8][4096][64]
  u16* Kt  = (u16*)(ws + 12845056);   //  4,194,304 B  [8][4096][64]
  u16* Vs  = (u16*)(ws + 17039360);   //  4,194,304 B  permuted V
  u16* Ot  = (u16*)(ws + 21233664);   //  4,194,304 B  [B][N][128]

  hipLaunchKernelGGL(k_prep_x, dim3(128, 8, 4), dim3(32, 8), 0, stream, x, xt);
  hipLaunchKernelGGL(k_prep_w, dim3(384), dim3(256), 0, stream, ew, ow, wbf, w2t);
  hipLaunchKernelGGL(k_qkv,  dim3(64, 6, 4), dim3(256), 0, stream, xt, wbf, eb, Qt, Kt, Vs);
  hipLaunchKernelGGL(k_attn, dim3(256),      dim3(1024), 0, stream, Qt, Kt, Vs, Ot);
  hipLaunchKernelGGL(k_out,  dim3(64, 4, 4), dim3(256), 0, stream, Ot, w2t, ob, x, out);
}